// Round 14
// baseline (1587.147 us; speedup 1.0000x reference)
//
#include <hip/hip_runtime.h>

// RecurrentSNN: B=256, T=1024, F=64, H=512, O=64
// out = concat(mem_rec [B,T,O], spk_rec [B,T,O]) f32.
//
// Round-14: scalar-pipe COUNT reduction (r11 diagnosis: ~33cy/s_load per-CU
// service rate; A/C are s_load-count-bound, not latency-bound — r12/r13's
// SGPR pipelining was both unverifiable (allocator copies of pending-load
// regs) and pointless).
//  - Load+wait merged into ONE asm (zero window, pure "=&s" defs).
//  A: 2 h/thread (4 waves cover 512 h) -> 16 s_loads/row (was 32).
//     128 pinned VGPR under waves_per_eu(2,2).
//  B: spikes exported as per-wave __ballot bitmask (8B/wave/row, 4MB total;
//     was 2KB/row f32). cur1 no longer overwritten.
//  C: 1 s_load_dwordx2/row/wave (was 4x dwordx16); unpack via
//     ((m>>k)&1)?1.0f:0.0f + fmaf — values identical (1.0/0.0), r5-proven.
//  D unchanged. fma chain order verbatim -> absmax exactly 0.04394531.

namespace {
constexpr int kB = 256;
constexpr int kT = 1024;
constexpr int kF = 64;
constexpr int kH = 512;
constexpr int kO = 64;
constexpr float kBeta = 0.9f;
constexpr float kThresh = 1.0f;
}  // namespace

typedef __attribute__((ext_vector_type(16))) float f32x16;
typedef __attribute__((ext_vector_type(2))) unsigned int u32x2;

#define PIN8(p)                                                            \
  asm volatile("" : "+v"((p)[0]), "+v"((p)[1]), "+v"((p)[2]),              \
                    "+v"((p)[3]), "+v"((p)[4]), "+v"((p)[5]),              \
                    "+v"((p)[6]), "+v"((p)[7]))

#define BARRIER() asm volatile("s_waitcnt lgkmcnt(0)\n\ts_barrier" ::: "memory")

// 64 floats -> 4 SGPR x16 banks, loads + drain in ONE asm (no window).
#define SLOAD64(sx0, sx1, sx2, sx3, ptr)                                   \
  asm volatile("s_load_dwordx16 %0, %4, 0x0\n\t"                           \
               "s_load_dwordx16 %1, %4, 0x40\n\t"                          \
               "s_load_dwordx16 %2, %4, 0x80\n\t"                          \
               "s_load_dwordx16 %3, %4, 0xc0\n\t"                          \
               "s_waitcnt lgkmcnt(0)"                                      \
               : "=&s"(sx0), "=&s"(sx1), "=&s"(sx2), "=&s"(sx3)            \
               : "s"(ptr) : "memory")

// ======================= A: cur1 = x @ W_in^T + b_in ======================
// 256 threads = 4 waves; thread (s,l): h0 = s*64+l, h1 = h0+256.
#define SX(i) ((i) < 16 ? sx0[(i)] : (i) < 32 ? sx1[(i)-16]                \
             : (i) < 48 ? sx2[(i)-32] : sx3[(i)-48])
#define AQ2(q)                                                             \
  c0 = fmaf(SX(4*(q)+0), wA[4*(q)+0], c0);                                 \
  c1 = fmaf(SX(4*(q)+1), wA[4*(q)+1], c1);                                 \
  c2 = fmaf(SX(4*(q)+2), wA[4*(q)+2], c2);                                 \
  c3 = fmaf(SX(4*(q)+3), wA[4*(q)+3], c3);                                 \
  e0 = fmaf(SX(4*(q)+0), wB[4*(q)+0], e0);                                 \
  e1 = fmaf(SX(4*(q)+1), wB[4*(q)+1], e1);                                 \
  e2 = fmaf(SX(4*(q)+2), wB[4*(q)+2], e2);                                 \
  e3 = fmaf(SX(4*(q)+3), wB[4*(q)+3], e3);

__global__ __launch_bounds__(256)
__attribute__((amdgpu_waves_per_eu(2, 2)))
void snn_curA(const float* __restrict__ x, const float* __restrict__ W_in,
              const float* __restrict__ b_in, float* __restrict__ cur1,
              int t0, int ntc, int l2ntc, int rpb) {
  const int l = threadIdx.x & 63;
  const int s = threadIdx.x >> 6;   // 0..3
  const int h0 = s * 64 + l;        // 0..255
  const int h1 = h0 + 256;          // 256..511

  float wA[64], wB[64];
  {
    const float4* w0 = reinterpret_cast<const float4*>(W_in) + h0 * 16;
    const float4* w1 = reinterpret_cast<const float4*>(W_in) + h1 * 16;
#pragma unroll
    for (int q = 0; q < 16; ++q) {
      const float4 a = w0[q];
      wA[4*q+0] = a.x; wA[4*q+1] = a.y; wA[4*q+2] = a.z; wA[4*q+3] = a.w;
      const float4 b = w1[q];
      wB[4*q+0] = b.x; wB[4*q+1] = b.y; wB[4*q+2] = b.z; wB[4*q+3] = b.w;
    }
  }
  float bin0 = b_in[h0], bin1 = b_in[h1];
  PIN8(wA + 0);  PIN8(wA + 8);  PIN8(wA + 16); PIN8(wA + 24);
  PIN8(wA + 32); PIN8(wA + 40); PIN8(wA + 48); PIN8(wA + 56);
  PIN8(wB + 0);  PIN8(wB + 8);  PIN8(wB + 16); PIN8(wB + 24);
  PIN8(wB + 32); PIN8(wB + 40); PIN8(wB + 48); PIN8(wB + 56);
  asm volatile("" : "+v"(bin0), "+v"(bin1));

  const int row0 = blockIdx.x * rpb;
#pragma unroll 1
  for (int r = 0; r < rpb; ++r) {
    const int row = row0 + r;
    const int b = row >> l2ntc;
    const int tc = row & (ntc - 1);
    const float* xp = x + ((size_t)b * kT + (size_t)(t0 + tc)) * kF;
    f32x16 sx0, sx1, sx2, sx3;
    SLOAD64(sx0, sx1, sx2, sx3, xp);
    float c0 = bin0, c1 = 0.0f, c2 = 0.0f, c3 = 0.0f;
    float e0 = bin1, e1 = 0.0f, e2 = 0.0f, e3 = 0.0f;
    AQ2(0) AQ2(1) AQ2(2) AQ2(3) AQ2(4) AQ2(5) AQ2(6) AQ2(7)
    AQ2(8) AQ2(9) AQ2(10) AQ2(11) AQ2(12) AQ2(13) AQ2(14) AQ2(15)
    float* cb = cur1 + (size_t)row * kH;
    cb[h0] = (c0 + c1) + (c2 + c3);
    cb[h1] = (e0 + e1) + (e2 + e3);
  }
}

// ======================= B: layer-1 scan -> spike bitmask =================
#define BSTEP(fk, tt)                                                      \
  do {                                                                     \
    mem1 = kBeta * mem1 + (fk) - rst1;                                     \
    const bool pr = mem1 > kThresh;                                        \
    const unsigned long long mk = __ballot(pr);                            \
    rst1 = pr ? 1.0f : 0.0f;                                               \
    if (l == 0)                                                            \
      *reinterpret_cast<unsigned long long*>(bitp + (size_t)(tt) * 16) = mk; \
    const int tn_ = ((tt) + 8 < ntc) ? (tt) + 8 : ntc - 1;                 \
    fk = cp[(size_t)tn_ * kH];                                             \
  } while (0)

__global__ __launch_bounds__(512)
void snn_scanB(const float* __restrict__ cs, unsigned int* __restrict__ bits,
               float* __restrict__ state, int t0, int ntc) {
  const int b = blockIdx.x;
  const int h = threadIdx.x;
  const int l = h & 63;
  const int w = h >> 6;
  float* m1s = state;
  float* r1s = state + kB * kH;
  const int idx = b * kH + h;
  float mem1 = 0.0f, rst1 = 0.0f;
  if (t0 != 0) { mem1 = m1s[idx]; rst1 = r1s[idx]; }

  const float* cp = cs + (size_t)b * ntc * kH + h;
  unsigned int* bitp = bits + (size_t)b * ntc * 16 + w * 2;

  float f0 = cp[0 * (size_t)kH], f1 = cp[1 * (size_t)kH];
  float f2 = cp[2 * (size_t)kH], f3 = cp[3 * (size_t)kH];
  float f4 = cp[4 * (size_t)kH], f5 = cp[5 * (size_t)kH];
  float f6 = cp[6 * (size_t)kH], f7 = cp[7 * (size_t)kH];

#pragma unroll 1
  for (int t = 0; t < ntc; t += 8) {
    BSTEP(f0, t + 0); BSTEP(f1, t + 1); BSTEP(f2, t + 2); BSTEP(f3, t + 3);
    BSTEP(f4, t + 4); BSTEP(f5, t + 5); BSTEP(f6, t + 6); BSTEP(f7, t + 7);
  }
  m1s[idx] = mem1;
  r1s[idx] = rst1;
}

// ======================= C: cur_out = spikes @ W_out^T + b_out ============
// Wave s, row r: 1 s_load_dwordx2 of the row's slice-s bitmask; unpack via
// ((m>>k)&1)?1.0f:0.0f (exact 1.0/0.0, r5-proven) + fmaf chains a0..a3.
#define FB(m, k) ((((m) >> (k)) & 1u) ? 1.0f : 0.0f)
#define CQL(q)                                                             \
  a0 = fmaf(FB(mlo, 4*(q)+0), wout[4*(q)+0], a0);                          \
  a1 = fmaf(FB(mlo, 4*(q)+1), wout[4*(q)+1], a1);                          \
  a2 = fmaf(FB(mlo, 4*(q)+2), wout[4*(q)+2], a2);                          \
  a3 = fmaf(FB(mlo, 4*(q)+3), wout[4*(q)+3], a3);
#define CQH(q)                                                             \
  a0 = fmaf(FB(mhi, 4*(q)+0-32), wout[4*(q)+0], a0);                       \
  a1 = fmaf(FB(mhi, 4*(q)+1-32), wout[4*(q)+1], a1);                       \
  a2 = fmaf(FB(mhi, 4*(q)+2-32), wout[4*(q)+2], a2);                       \
  a3 = fmaf(FB(mhi, 4*(q)+3-32), wout[4*(q)+3], a3);

__global__ __launch_bounds__(512)
__attribute__((amdgpu_waves_per_eu(2, 2)))
void snn_coutC(const unsigned int* __restrict__ bits,
               const float* __restrict__ W_out,
               const float* __restrict__ b_out, float* __restrict__ cout,
               int ntc) {
  const int j = threadIdx.x;
  const int o = j & 63;
  const int s = j >> 6;
  const int s_u = __builtin_amdgcn_readfirstlane(s);
  const size_t row0 = (size_t)blockIdx.x * 64;

  __shared__ float red[2][8][8][64];  // [buf][rowInBatch][slice][o]

  float wout[64];
  {
    const float4* wov =
        reinterpret_cast<const float4*>(W_out) + o * (kH / 4) + s * 16;
#pragma unroll
    for (int q = 0; q < 16; ++q) {
      const float4 v = wov[q];
      wout[4*q+0] = v.x; wout[4*q+1] = v.y;
      wout[4*q+2] = v.z; wout[4*q+3] = v.w;
    }
  }
  float bout = b_out[o];
  PIN8(wout + 0);  PIN8(wout + 8);  PIN8(wout + 16); PIN8(wout + 24);
  PIN8(wout + 32); PIN8(wout + 40); PIN8(wout + 48); PIN8(wout + 56);
  asm volatile("" : "+v"(bout));

  const unsigned int* bitbase = bits + row0 * 16 + s_u * 2;

#pragma unroll 1
  for (int rb = 0; rb < 64; rb += 8) {
    const int buf = (rb >> 3) & 1;
#pragma unroll
    for (int r = 0; r < 8; ++r) {
      const unsigned int* bp = bitbase + (size_t)(rb + r) * 16;
      u32x2 mm;
      asm volatile("s_load_dwordx2 %0, %1, 0x0\n\t"
                   "s_waitcnt lgkmcnt(0)"
                   : "=&s"(mm) : "s"(bp) : "memory");
      const unsigned int mlo = mm[0];
      const unsigned int mhi = mm[1];
      float a0 = 0.0f, a1 = 0.0f, a2 = 0.0f, a3 = 0.0f;
      CQL(0) CQL(1) CQL(2) CQL(3) CQL(4) CQL(5) CQL(6) CQL(7)
      CQH(8) CQH(9) CQH(10) CQH(11) CQH(12) CQH(13) CQH(14) CQH(15)
      red[buf][r][s][o] = (a0 + a1) + (a2 + a3);
    }
    BARRIER();

    float co = bout;
    co += red[buf][s][0][o]; co += red[buf][s][1][o];
    co += red[buf][s][2][o]; co += red[buf][s][3][o];
    co += red[buf][s][4][o]; co += red[buf][s][5][o];
    co += red[buf][s][6][o]; co += red[buf][s][7][o];
    cout[(row0 + (size_t)(rb + s)) * kO + o] = co;
  }
}

// ======================= D: layer-2 scan (per b,o) ========================
#define DSTEP(gk, tt)                                                      \
  do {                                                                     \
    memo = kBeta * memo + (gk) - rsto;                                     \
    const float so = (memo > kThresh) ? 1.0f : 0.0f;                       \
    rsto = so;                                                             \
    om[(size_t)(tt) * kO] = memo;                                          \
    os[(size_t)(tt) * kO] = so;                                            \
    const int tn_ = ((tt) + 8 < ntc) ? (tt) + 8 : ntc - 1;                 \
    gk = dp[(size_t)tn_ * kO];                                             \
  } while (0)

__global__ __launch_bounds__(64)
void snn_memoD(const float* __restrict__ cout, float* __restrict__ out,
               float* __restrict__ state, int t0, int ntc) {
  const int b = blockIdx.x;
  const int o = threadIdx.x;
  float* mos = state + 2 * kB * kH;
  float* ros = mos + kB * kO;
  const int idx = b * kO + o;
  float memo = 0.0f, rsto = 0.0f;
  if (t0 != 0) { memo = mos[idx]; rsto = ros[idx]; }

  const float* dp = cout + (size_t)b * ntc * kO + o;
  float* om = out + ((size_t)b * kT + t0) * kO + o;
  float* os = om + (size_t)kB * kT * kO;

  float g0 = dp[0 * (size_t)kO], g1 = dp[1 * (size_t)kO];
  float g2 = dp[2 * (size_t)kO], g3 = dp[3 * (size_t)kO];
  float g4 = dp[4 * (size_t)kO], g5 = dp[5 * (size_t)kO];
  float g6 = dp[6 * (size_t)kO], g7 = dp[7 * (size_t)kO];

#pragma unroll 1
  for (int t = 0; t < ntc; t += 8) {
    DSTEP(g0, t + 0); DSTEP(g1, t + 1); DSTEP(g2, t + 2); DSTEP(g3, t + 3);
    DSTEP(g4, t + 4); DSTEP(g5, t + 5); DSTEP(g6, t + 6); DSTEP(g7, t + 7);
  }
  mos[idx] = memo;
  ros[idx] = rsto;
}

// ======================= fallback (round-5, proven 1101us) ================
__global__ __launch_bounds__(256)
void warm_x_kernel(const float4* __restrict__ p, int n4) {
  float acc = 0.0f;
  for (int i = blockIdx.x * blockDim.x + threadIdx.x; i < n4;
       i += gridDim.x * blockDim.x) {
    const float4 v = p[i];
    acc += v.x + v.y + v.z + v.w;
  }
  asm volatile("" ::"v"(acc));
}

__global__ __launch_bounds__(512)
__attribute__((amdgpu_waves_per_eu(2, 2)))
void snn_fused5(const float* __restrict__ x, const float* __restrict__ W_in,
                const float* __restrict__ b_in,
                const float* __restrict__ W_out,
                const float* __restrict__ b_out, float* __restrict__ out) {
  const int b = blockIdx.x;
  const int j = threadIdx.x;
  const int o = j & 63;
  const int s = j >> 6;
  __shared__ float red[2][8][64];
  float win[kF];
  {
    const float4* wiv = reinterpret_cast<const float4*>(W_in) + j * 16;
#pragma unroll
    for (int q = 0; q < 16; ++q) {
      const float4 v = wiv[q];
      win[4 * q] = v.x; win[4 * q + 1] = v.y;
      win[4 * q + 2] = v.z; win[4 * q + 3] = v.w;
    }
  }
  float wout[64];
  {
    const float4* wov =
        reinterpret_cast<const float4*>(W_out) + o * 128 + s * 16;
#pragma unroll
    for (int q = 0; q < 16; ++q) {
      const float4 v = wov[q];
      wout[4 * q] = v.x; wout[4 * q + 1] = v.y;
      wout[4 * q + 2] = v.z; wout[4 * q + 3] = v.w;
    }
  }
  float bin_j = b_in[j];
  float bout_o = b_out[o];
  PIN8(win + 0);  PIN8(win + 8);  PIN8(win + 16); PIN8(win + 24);
  PIN8(win + 32); PIN8(win + 40); PIN8(win + 48); PIN8(win + 56);
  PIN8(wout + 0);  PIN8(wout + 8);  PIN8(wout + 16); PIN8(wout + 24);
  PIN8(wout + 32); PIN8(wout + 40); PIN8(wout + 48); PIN8(wout + 56);
  asm volatile("" : "+v"(bin_j), "+v"(bout_o));
  float mem1 = 0.0f, rst1 = 0.0f, memo = 0.0f, rsto = 0.0f;
  unsigned long long mask = 0ull;
  const float4* xv = reinterpret_cast<const float4*>(x + (size_t)b * kT * kF);
  float* out_mem = out + (size_t)b * kT * kO + o;
  float* out_spk = out_mem + (size_t)kB * kT * kO;
  float4 x0, x1, x2, x3, x4, x5, x6, x7, x8, x9, x10, x11, x12, x13, x14, x15;
#define LOADX(tt)                                                          \
  do {                                                                     \
    const float4* xp = xv + (size_t)(tt) * 16;                             \
    x0 = xp[0]; x1 = xp[1]; x2 = xp[2]; x3 = xp[3];                        \
    x4 = xp[4]; x5 = xp[5]; x6 = xp[6]; x7 = xp[7];                        \
    x8 = xp[8]; x9 = xp[9]; x10 = xp[10]; x11 = xp[11];                    \
    x12 = xp[12]; x13 = xp[13]; x14 = xp[14]; x15 = xp[15];                \
  } while (0)
#define L1Q(q)                                                             \
  c0 = fmaf(x##q.x, win[4 * q + 0], c0);                                   \
  c1 = fmaf(x##q.y, win[4 * q + 1], c1);                                   \
  c2 = fmaf(x##q.z, win[4 * q + 2], c2);                                   \
  c3 = fmaf(x##q.w, win[4 * q + 3], c3);
#define LAYER1F()                                                          \
  do {                                                                     \
    float c0 = bin_j, c1 = 0.0f, c2 = 0.0f, c3 = 0.0f;                     \
    L1Q(0) L1Q(1) L1Q(2) L1Q(3) L1Q(4) L1Q(5) L1Q(6) L1Q(7)                \
    L1Q(8) L1Q(9) L1Q(10) L1Q(11) L1Q(12) L1Q(13) L1Q(14) L1Q(15)          \
    const float cur1v = (c0 + c1) + (c2 + c3);                             \
    mem1 = kBeta * mem1 + cur1v - rst1;                                    \
    const bool p = mem1 > kThresh;                                         \
    mask = __ballot(p);                                                    \
    rst1 = p ? 1.0f : 0.0f;                                                \
  } while (0)
#define L2QS(q)                                                            \
  {                                                                        \
    const float f0 = ((mlo >> (4 * (q) + 0)) & 1u) ? 1.0f : 0.0f;          \
    const float f1 = ((mlo >> (4 * (q) + 1)) & 1u) ? 1.0f : 0.0f;          \
    const float f2 = ((mlo >> (4 * (q) + 2)) & 1u) ? 1.0f : 0.0f;          \
    const float f3 = ((mlo >> (4 * (q) + 3)) & 1u) ? 1.0f : 0.0f;          \
    a0 = fmaf(f0, wout[4 * (q) + 0], a0);                                  \
    a1 = fmaf(f1, wout[4 * (q) + 1], a1);                                  \
    a2 = fmaf(f2, wout[4 * (q) + 2], a2);                                  \
    a3 = fmaf(f3, wout[4 * (q) + 3], a3);                                  \
  }
#define L2E(acc, q, i)                                                     \
  acc = acc + __uint_as_float(                                             \
      (unsigned)__builtin_amdgcn_sbfe((int)vmhi, 4 * (q) + (i)-32, 1) &    \
      __float_as_uint(wout[4 * (q) + (i)]));
#define L2QV(q)                                                            \
  { L2E(a0, q, 0) L2E(a1, q, 1) L2E(a2, q, 2) L2E(a3, q, 3) }
#define LAYER2F(buf)                                                       \
  do {                                                                     \
    const unsigned mlo = (unsigned)mask;                                   \
    unsigned vmhi = (unsigned)(mask >> 32);                                \
    asm volatile("" : "+v"(vmhi));                                         \
    float a0 = 0.0f, a1 = 0.0f, a2 = 0.0f, a3 = 0.0f;                      \
    L2QS(0) L2QS(1) L2QS(2) L2QS(3) L2QS(4) L2QS(5) L2QS(6) L2QS(7)        \
    L2QV(8) L2QV(9) L2QV(10) L2QV(11) L2QV(12) L2QV(13) L2QV(14) L2QV(15)  \
    red[(buf)][s][o] = (a0 + a1) + (a2 + a3);                              \
  } while (0)
  LOADX(0);
  LAYER1F();
  LOADX(1);
  for (int t = 1; t < kT; ++t) {
    LAYER2F((t - 1) & 1);
    BARRIER();
    float r0, r1, r2, r3, r4, r5, r6, r7;
    const int buf = (t - 1) & 1;
    if (s == 0) {
      r0 = red[buf][0][o]; r1 = red[buf][1][o];
      r2 = red[buf][2][o]; r3 = red[buf][3][o];
      r4 = red[buf][4][o]; r5 = red[buf][5][o];
      r6 = red[buf][6][o]; r7 = red[buf][7][o];
    }
    LAYER1F();
    const int tn = (t + 1 < kT) ? (t + 1) : (kT - 1);
    LOADX(tn);
    if (s == 0) {
      float co = bout_o;
      co += r0; co += r1; co += r2; co += r3;
      co += r4; co += r5; co += r6; co += r7;
      memo = kBeta * memo + co - rsto;
      const float so = (memo > kThresh) ? 1.0f : 0.0f;
      rsto = so;
      out_mem[(t - 1) * kO] = memo;
      out_spk[(t - 1) * kO] = so;
    }
  }
  LAYER2F((kT - 1) & 1);
  BARRIER();
  if (s == 0) {
    const int buf = (kT - 1) & 1;
    float co = bout_o;
    co += red[buf][0][o]; co += red[buf][1][o];
    co += red[buf][2][o]; co += red[buf][3][o];
    co += red[buf][4][o]; co += red[buf][5][o];
    co += red[buf][6][o]; co += red[buf][7][o];
    memo = kBeta * memo + co - rsto;
    const float so = (memo > kThresh) ? 1.0f : 0.0f;
    out_mem[(kT - 1) * kO] = memo;
    out_spk[(kT - 1) * kO] = so;
  }
}

// ======================= host ==============================================
extern "C" void kernel_launch(void* const* d_in, const int* in_sizes, int n_in,
                              void* d_out, int out_size, void* d_ws,
                              size_t ws_size, hipStream_t stream) {
  const float* x = (const float*)d_in[0];
  const float* W_in = (const float*)d_in[1];
  const float* b_in = (const float*)d_in[2];
  const float* W_out = (const float*)d_in[3];
  const float* b_out = (const float*)d_in[4];
  float* out = (float*)d_out;

  const size_t state_bytes = ((size_t)2 * kB * kH + 2 * kB * kO) * 4;
  int nch = 0;
  for (int c : {2, 4, 8, 16}) {
    const int ntc_c = kT / c;
    const size_t rows_c = (size_t)kB * ntc_c;
    const size_t need =
        rows_c * (kH + kO) * 4 + rows_c * 16 * 4 + state_bytes;
    if (need <= ws_size) { nch = c; break; }
  }

  if (nch) {
    const int ntc = kT / nch;
    const int l2ntc = (ntc == 512) ? 9 : (ntc == 256) ? 8
                     : (ntc == 128) ? 7 : 6;
    const size_t rows = (size_t)kB * ntc;
    float* cur1 = (float*)d_ws;
    float* coutb = cur1 + rows * kH;
    unsigned int* bitsb = (unsigned int*)(coutb + rows * kO);
    float* state = (float*)(bitsb + rows * 16);

    const int rpbA = 64;
    const int gA = (int)(rows / rpbA);
    const int gC = (int)(rows / 64);

    for (int c = 0; c < nch; ++c) {
      const int t0 = c * ntc;
      hipLaunchKernelGGL(snn_curA, dim3(gA), dim3(256), 0, stream,
                         x, W_in, b_in, cur1, t0, ntc, l2ntc, rpbA);
      hipLaunchKernelGGL(snn_scanB, dim3(kB), dim3(512), 0, stream,
                         cur1, bitsb, state, t0, ntc);
      hipLaunchKernelGGL(snn_coutC, dim3(gC), dim3(512), 0, stream,
                         bitsb, W_out, b_out, coutb, ntc);
      hipLaunchKernelGGL(snn_memoD, dim3(kB), dim3(64), 0, stream,
                         coutb, out, state, t0, ntc);
    }
  } else {
    const int n4 = kB * kT * kF / 4;
    hipLaunchKernelGGL(warm_x_kernel, dim3(1024), dim3(256), 0, stream,
                       (const float4*)x, n4);
    hipLaunchKernelGGL(snn_fused5, dim3(kB), dim3(512), 0, stream,
                       x, W_in, b_in, W_out, b_out, out);
  }
}

// Round 15
// 1094.309 us; speedup vs baseline: 1.4504x; 1.4504x over previous
//
#include <hip/hip_runtime.h>

// RecurrentSNN: B=256, T=1024, F=64, H=512, O=64
// out = concat(mem_rec [B,T,O], spk_rec [B,T,O]) f32.
//
// Round-15: recombination of measured-good parts. r11 counters fit a
// per-CU scalar-pipe service model (~33cy per s_load inst): A and C were
// both s_load-COUNT bound at default occupancy. r14 proved (a) 2h/thread
// A passes (halves A's count), (b) waves_per_eu(2,2)+nch=2 destroys C.
//  A: r14's 2h/thread (256 thr, 4 waves -> 16 s_loads/row, was 32).
//  B: r11's scan (f32 spikes overwrite cur1 in place).
//  C: r11's scalar-pipe C verbatim (default occupancy -- the TLP covers
//     the zero-window waits; 113us/chunk measured).
//  D: unchanged. Host: probe {4,8,16} only (nch=2 spills L3).
// All fma chains verbatim -> absmax exactly 0.04394531.

namespace {
constexpr int kB = 256;
constexpr int kT = 1024;
constexpr int kF = 64;
constexpr int kH = 512;
constexpr int kO = 64;
constexpr float kBeta = 0.9f;
constexpr float kThresh = 1.0f;
}  // namespace

typedef __attribute__((ext_vector_type(16))) float f32x16;

#define PIN8(p)                                                            \
  asm volatile("" : "+v"((p)[0]), "+v"((p)[1]), "+v"((p)[2]),              \
                    "+v"((p)[3]), "+v"((p)[4]), "+v"((p)[5]),              \
                    "+v"((p)[6]), "+v"((p)[7]))

#define BARRIER() asm volatile("s_waitcnt lgkmcnt(0)\n\ts_barrier" ::: "memory")

// 64 floats -> 4 SGPR x16 banks, loads + drain in ONE asm (zero window:
// no instruction may sit between the loads and the wait -> allocator
// cannot touch pending-load registers; r12/r13 lesson).
#define SLOAD64(sx0, sx1, sx2, sx3, ptr)                                   \
  asm volatile("s_load_dwordx16 %0, %4, 0x0\n\t"                           \
               "s_load_dwordx16 %1, %4, 0x40\n\t"                          \
               "s_load_dwordx16 %2, %4, 0x80\n\t"                          \
               "s_load_dwordx16 %3, %4, 0xc0\n\t"                          \
               "s_waitcnt lgkmcnt(0)"                                      \
               : "=&s"(sx0), "=&s"(sx1), "=&s"(sx2), "=&s"(sx3)            \
               : "s"(ptr) : "memory")

// ======================= A: cur1 = x @ W_in^T + b_in ======================
// 256 threads = 4 waves; thread (s,l): h0 = s*64+l, h1 = h0+256.
#define SX(i) ((i) < 16 ? sx0[(i)] : (i) < 32 ? sx1[(i)-16]                \
             : (i) < 48 ? sx2[(i)-32] : sx3[(i)-48])
#define AQ2(q)                                                             \
  c0 = fmaf(SX(4*(q)+0), wA[4*(q)+0], c0);                                 \
  c1 = fmaf(SX(4*(q)+1), wA[4*(q)+1], c1);                                 \
  c2 = fmaf(SX(4*(q)+2), wA[4*(q)+2], c2);                                 \
  c3 = fmaf(SX(4*(q)+3), wA[4*(q)+3], c3);                                 \
  e0 = fmaf(SX(4*(q)+0), wB[4*(q)+0], e0);                                 \
  e1 = fmaf(SX(4*(q)+1), wB[4*(q)+1], e1);                                 \
  e2 = fmaf(SX(4*(q)+2), wB[4*(q)+2], e2);                                 \
  e3 = fmaf(SX(4*(q)+3), wB[4*(q)+3], e3);

__global__ __launch_bounds__(256)
__attribute__((amdgpu_waves_per_eu(2, 2)))
void snn_curA(const float* __restrict__ x, const float* __restrict__ W_in,
              const float* __restrict__ b_in, float* __restrict__ cur1,
              int t0, int ntc, int l2ntc, int rpb) {
  const int l = threadIdx.x & 63;
  const int s = threadIdx.x >> 6;   // 0..3
  const int h0 = s * 64 + l;        // 0..255
  const int h1 = h0 + 256;          // 256..511

  float wA[64], wB[64];
  {
    const float4* w0 = reinterpret_cast<const float4*>(W_in) + h0 * 16;
    const float4* w1 = reinterpret_cast<const float4*>(W_in) + h1 * 16;
#pragma unroll
    for (int q = 0; q < 16; ++q) {
      const float4 a = w0[q];
      wA[4*q+0] = a.x; wA[4*q+1] = a.y; wA[4*q+2] = a.z; wA[4*q+3] = a.w;
      const float4 b = w1[q];
      wB[4*q+0] = b.x; wB[4*q+1] = b.y; wB[4*q+2] = b.z; wB[4*q+3] = b.w;
    }
  }
  float bin0 = b_in[h0], bin1 = b_in[h1];
  PIN8(wA + 0);  PIN8(wA + 8);  PIN8(wA + 16); PIN8(wA + 24);
  PIN8(wA + 32); PIN8(wA + 40); PIN8(wA + 48); PIN8(wA + 56);
  PIN8(wB + 0);  PIN8(wB + 8);  PIN8(wB + 16); PIN8(wB + 24);
  PIN8(wB + 32); PIN8(wB + 40); PIN8(wB + 48); PIN8(wB + 56);
  asm volatile("" : "+v"(bin0), "+v"(bin1));

  const int row0 = blockIdx.x * rpb;
#pragma unroll 1
  for (int r = 0; r < rpb; ++r) {
    const int row = row0 + r;
    const int b = row >> l2ntc;
    const int tc = row & (ntc - 1);
    const float* xp = x + ((size_t)b * kT + (size_t)(t0 + tc)) * kF;
    f32x16 sx0, sx1, sx2, sx3;
    SLOAD64(sx0, sx1, sx2, sx3, xp);
    float c0 = bin0, c1 = 0.0f, c2 = 0.0f, c3 = 0.0f;
    float e0 = bin1, e1 = 0.0f, e2 = 0.0f, e3 = 0.0f;
    AQ2(0) AQ2(1) AQ2(2) AQ2(3) AQ2(4) AQ2(5) AQ2(6) AQ2(7)
    AQ2(8) AQ2(9) AQ2(10) AQ2(11) AQ2(12) AQ2(13) AQ2(14) AQ2(15)
    float* cb = cur1 + (size_t)row * kH;
    cb[h0] = (c0 + c1) + (c2 + c3);
    cb[h1] = (e0 + e1) + (e2 + e3);
  }
}

// ======================= B: layer-1 scan (per b,h) ========================
#define BSTEP(fk, tt)                                                      \
  do {                                                                     \
    mem1 = kBeta * mem1 + (fk) - rst1;                                     \
    const bool pr = mem1 > kThresh;                                        \
    rst1 = pr ? 1.0f : 0.0f;                                               \
    cp[(size_t)(tt) * kH] = rst1;  /* spike overwrites cur1 slot */        \
    const int tn_ = ((tt) + 8 < ntc) ? (tt) + 8 : ntc - 1;                 \
    fk = cp[(size_t)tn_ * kH];     /* prefetch (clamped ones unused) */    \
  } while (0)

__global__ __launch_bounds__(512)
void snn_scanB(float* __restrict__ cs, float* __restrict__ state,
               int t0, int ntc) {
  const int b = blockIdx.x;
  const int h = threadIdx.x;
  float* m1s = state;
  float* r1s = state + kB * kH;
  const int idx = b * kH + h;
  float mem1 = 0.0f, rst1 = 0.0f;
  if (t0 != 0) { mem1 = m1s[idx]; rst1 = r1s[idx]; }

  float* cp = cs + (size_t)b * ntc * kH + h;
  float f0 = cp[0 * (size_t)kH], f1 = cp[1 * (size_t)kH];
  float f2 = cp[2 * (size_t)kH], f3 = cp[3 * (size_t)kH];
  float f4 = cp[4 * (size_t)kH], f5 = cp[5 * (size_t)kH];
  float f6 = cp[6 * (size_t)kH], f7 = cp[7 * (size_t)kH];

#pragma unroll 1
  for (int t = 0; t < ntc; t += 8) {
    BSTEP(f0, t + 0); BSTEP(f1, t + 1); BSTEP(f2, t + 2); BSTEP(f3, t + 3);
    BSTEP(f4, t + 4); BSTEP(f5, t + 5); BSTEP(f6, t + 6); BSTEP(f7, t + 7);
  }
  m1s[idx] = mem1;
  r1s[idx] = rst1;
}

// ======================= C: cur_out = spikes @ W_out^T + b_out ============
// r11 verbatim: wave s reads its slice's spikes (256B wave-uniform, SGPR
// address via readfirstlane) with one merged 4x s_load_dwordx16 + wait;
// default occupancy gives the TLP that hides the zero-window waits.
#define SC(i) ((i) < 16 ? m0[(i)] : (i) < 32 ? m1[(i)-16]                  \
             : (i) < 48 ? m2[(i)-32] : m3[(i)-48])

#define CROW(rr)                                                           \
  do {                                                                     \
    const float* sp = spkrow + (size_t)(rr) * kH;                          \
    f32x16 m0, m1, m2, m3;                                                 \
    SLOAD64(m0, m1, m2, m3, sp);                                           \
    float a0 = 0.0f, a1 = 0.0f, a2 = 0.0f, a3 = 0.0f;                      \
    _Pragma("unroll") for (int q = 0; q < 16; ++q) {                       \
      a0 = fmaf(SC(4 * q + 0), wout[4 * q + 0], a0);                       \
      a1 = fmaf(SC(4 * q + 1), wout[4 * q + 1], a1);                       \
      a2 = fmaf(SC(4 * q + 2), wout[4 * q + 2], a2);                       \
      a3 = fmaf(SC(4 * q + 3), wout[4 * q + 3], a3);                       \
    }                                                                      \
    red[buf][rr][s][o] = (a0 + a1) + (a2 + a3);                            \
  } while (0)

__global__ __launch_bounds__(512)
void snn_coutC(const float* __restrict__ spk, const float* __restrict__ W_out,
               const float* __restrict__ b_out, float* __restrict__ cout,
               int ntc) {
  const int j = threadIdx.x;
  const int o = j & 63;
  const int s = j >> 6;
  const int s_u = __builtin_amdgcn_readfirstlane(s);  // SGPR-addressable
  const size_t row0 = (size_t)blockIdx.x * 64;

  __shared__ float red[2][8][8][64];  // [buf][rowInBatch][slice][o]

  float wout[64];
  {
    const float4* wov =
        reinterpret_cast<const float4*>(W_out) + o * (kH / 4) + s * 16;
#pragma unroll
    for (int q = 0; q < 16; ++q) {
      const float4 v = wov[q];
      wout[4*q+0] = v.x; wout[4*q+1] = v.y;
      wout[4*q+2] = v.z; wout[4*q+3] = v.w;
    }
  }
  float bout = b_out[o];
  PIN8(wout + 0);  PIN8(wout + 8);  PIN8(wout + 16); PIN8(wout + 24);
  PIN8(wout + 32); PIN8(wout + 40); PIN8(wout + 48); PIN8(wout + 56);
  asm volatile("" : "+v"(bout));

#pragma unroll 1
  for (int rb = 0; rb < 64; rb += 8) {
    const int buf = (rb >> 3) & 1;
    const float* spkrow = spk + (row0 + (size_t)rb) * kH + s_u * 64;

    CROW(0); CROW(1); CROW(2); CROW(3);
    CROW(4); CROW(5); CROW(6); CROW(7);

    BARRIER();  // red visible; single barrier per batch (dbuf separation)

    // wave s reduces row rb+s and stores (coalesced 256B)
    float co = bout;
    co += red[buf][s][0][o]; co += red[buf][s][1][o];
    co += red[buf][s][2][o]; co += red[buf][s][3][o];
    co += red[buf][s][4][o]; co += red[buf][s][5][o];
    co += red[buf][s][6][o]; co += red[buf][s][7][o];
    cout[(row0 + (size_t)(rb + s)) * kO + o] = co;
  }
}

// ======================= D: layer-2 scan (per b,o) ========================
#define DSTEP(gk, tt)                                                      \
  do {                                                                     \
    memo = kBeta * memo + (gk) - rsto;                                     \
    const float so = (memo > kThresh) ? 1.0f : 0.0f;                       \
    rsto = so;                                                             \
    om[(size_t)(tt) * kO] = memo;                                          \
    os[(size_t)(tt) * kO] = so;                                            \
    const int tn_ = ((tt) + 8 < ntc) ? (tt) + 8 : ntc - 1;                 \
    gk = dp[(size_t)tn_ * kO];                                             \
  } while (0)

__global__ __launch_bounds__(64)
void snn_memoD(const float* __restrict__ cout, float* __restrict__ out,
               float* __restrict__ state, int t0, int ntc) {
  const int b = blockIdx.x;
  const int o = threadIdx.x;
  float* mos = state + 2 * kB * kH;
  float* ros = mos + kB * kO;
  const int idx = b * kO + o;
  float memo = 0.0f, rsto = 0.0f;
  if (t0 != 0) { memo = mos[idx]; rsto = ros[idx]; }

  const float* dp = cout + (size_t)b * ntc * kO + o;
  float* om = out + ((size_t)b * kT + t0) * kO + o;
  float* os = om + (size_t)kB * kT * kO;

  float g0 = dp[0 * (size_t)kO], g1 = dp[1 * (size_t)kO];
  float g2 = dp[2 * (size_t)kO], g3 = dp[3 * (size_t)kO];
  float g4 = dp[4 * (size_t)kO], g5 = dp[5 * (size_t)kO];
  float g6 = dp[6 * (size_t)kO], g7 = dp[7 * (size_t)kO];

#pragma unroll 1
  for (int t = 0; t < ntc; t += 8) {
    DSTEP(g0, t + 0); DSTEP(g1, t + 1); DSTEP(g2, t + 2); DSTEP(g3, t + 3);
    DSTEP(g4, t + 4); DSTEP(g5, t + 5); DSTEP(g6, t + 6); DSTEP(g7, t + 7);
  }
  mos[idx] = memo;
  ros[idx] = rsto;
}

// ======================= fallback (round-5, proven 1101us) ================
__global__ __launch_bounds__(256)
void warm_x_kernel(const float4* __restrict__ p, int n4) {
  float acc = 0.0f;
  for (int i = blockIdx.x * blockDim.x + threadIdx.x; i < n4;
       i += gridDim.x * blockDim.x) {
    const float4 v = p[i];
    acc += v.x + v.y + v.z + v.w;
  }
  asm volatile("" ::"v"(acc));
}

__global__ __launch_bounds__(512)
__attribute__((amdgpu_waves_per_eu(2, 2)))
void snn_fused5(const float* __restrict__ x, const float* __restrict__ W_in,
                const float* __restrict__ b_in,
                const float* __restrict__ W_out,
                const float* __restrict__ b_out, float* __restrict__ out) {
  const int b = blockIdx.x;
  const int j = threadIdx.x;
  const int o = j & 63;
  const int s = j >> 6;
  __shared__ float red[2][8][64];
  float win[kF];
  {
    const float4* wiv = reinterpret_cast<const float4*>(W_in) + j * 16;
#pragma unroll
    for (int q = 0; q < 16; ++q) {
      const float4 v = wiv[q];
      win[4 * q] = v.x; win[4 * q + 1] = v.y;
      win[4 * q + 2] = v.z; win[4 * q + 3] = v.w;
    }
  }
  float wout[64];
  {
    const float4* wov =
        reinterpret_cast<const float4*>(W_out) + o * 128 + s * 16;
#pragma unroll
    for (int q = 0; q < 16; ++q) {
      const float4 v = wov[q];
      wout[4 * q] = v.x; wout[4 * q + 1] = v.y;
      wout[4 * q + 2] = v.z; wout[4 * q + 3] = v.w;
    }
  }
  float bin_j = b_in[j];
  float bout_o = b_out[o];
  PIN8(win + 0);  PIN8(win + 8);  PIN8(win + 16); PIN8(win + 24);
  PIN8(win + 32); PIN8(win + 40); PIN8(win + 48); PIN8(win + 56);
  PIN8(wout + 0);  PIN8(wout + 8);  PIN8(wout + 16); PIN8(wout + 24);
  PIN8(wout + 32); PIN8(wout + 40); PIN8(wout + 48); PIN8(wout + 56);
  asm volatile("" : "+v"(bin_j), "+v"(bout_o));
  float mem1 = 0.0f, rst1 = 0.0f, memo = 0.0f, rsto = 0.0f;
  unsigned long long mask = 0ull;
  const float4* xv = reinterpret_cast<const float4*>(x + (size_t)b * kT * kF);
  float* out_mem = out + (size_t)b * kT * kO + o;
  float* out_spk = out_mem + (size_t)kB * kT * kO;
  float4 x0, x1, x2, x3, x4, x5, x6, x7, x8, x9, x10, x11, x12, x13, x14, x15;
#define LOADX(tt)                                                          \
  do {                                                                     \
    const float4* xp = xv + (size_t)(tt) * 16;                             \
    x0 = xp[0]; x1 = xp[1]; x2 = xp[2]; x3 = xp[3];                        \
    x4 = xp[4]; x5 = xp[5]; x6 = xp[6]; x7 = xp[7];                        \
    x8 = xp[8]; x9 = xp[9]; x10 = xp[10]; x11 = xp[11];                    \
    x12 = xp[12]; x13 = xp[13]; x14 = xp[14]; x15 = xp[15];                \
  } while (0)
#define L1Q(q)                                                             \
  c0 = fmaf(x##q.x, win[4 * q + 0], c0);                                   \
  c1 = fmaf(x##q.y, win[4 * q + 1], c1);                                   \
  c2 = fmaf(x##q.z, win[4 * q + 2], c2);                                   \
  c3 = fmaf(x##q.w, win[4 * q + 3], c3);
#define LAYER1F()                                                          \
  do {                                                                     \
    float c0 = bin_j, c1 = 0.0f, c2 = 0.0f, c3 = 0.0f;                     \
    L1Q(0) L1Q(1) L1Q(2) L1Q(3) L1Q(4) L1Q(5) L1Q(6) L1Q(7)                \
    L1Q(8) L1Q(9) L1Q(10) L1Q(11) L1Q(12) L1Q(13) L1Q(14) L1Q(15)          \
    const float cur1v = (c0 + c1) + (c2 + c3);                             \
    mem1 = kBeta * mem1 + cur1v - rst1;                                    \
    const bool p = mem1 > kThresh;                                         \
    mask = __ballot(p);                                                    \
    rst1 = p ? 1.0f : 0.0f;                                                \
  } while (0)
#define L2QS(q)                                                            \
  {                                                                        \
    const float f0 = ((mlo >> (4 * (q) + 0)) & 1u) ? 1.0f : 0.0f;          \
    const float f1 = ((mlo >> (4 * (q) + 1)) & 1u) ? 1.0f : 0.0f;          \
    const float f2 = ((mlo >> (4 * (q) + 2)) & 1u) ? 1.0f : 0.0f;          \
    const float f3 = ((mlo >> (4 * (q) + 3)) & 1u) ? 1.0f : 0.0f;          \
    a0 = fmaf(f0, wout[4 * (q) + 0], a0);                                  \
    a1 = fmaf(f1, wout[4 * (q) + 1], a1);                                  \
    a2 = fmaf(f2, wout[4 * (q) + 2], a2);                                  \
    a3 = fmaf(f3, wout[4 * (q) + 3], a3);                                  \
  }
#define L2E(acc, q, i)                                                     \
  acc = acc + __uint_as_float(                                             \
      (unsigned)__builtin_amdgcn_sbfe((int)vmhi, 4 * (q) + (i)-32, 1) &    \
      __float_as_uint(wout[4 * (q) + (i)]));
#define L2QV(q)                                                            \
  { L2E(a0, q, 0) L2E(a1, q, 1) L2E(a2, q, 2) L2E(a3, q, 3) }
#define LAYER2F(buf)                                                       \
  do {                                                                     \
    const unsigned mlo = (unsigned)mask;                                   \
    unsigned vmhi = (unsigned)(mask >> 32);                                \
    asm volatile("" : "+v"(vmhi));                                         \
    float a0 = 0.0f, a1 = 0.0f, a2 = 0.0f, a3 = 0.0f;                      \
    L2QS(0) L2QS(1) L2QS(2) L2QS(3) L2QS(4) L2QS(5) L2QS(6) L2QS(7)        \
    L2QV(8) L2QV(9) L2QV(10) L2QV(11) L2QV(12) L2QV(13) L2QV(14) L2QV(15)  \
    red[(buf)][s][o] = (a0 + a1) + (a2 + a3);                              \
  } while (0)
  LOADX(0);
  LAYER1F();
  LOADX(1);
  for (int t = 1; t < kT; ++t) {
    LAYER2F((t - 1) & 1);
    BARRIER();
    float r0, r1, r2, r3, r4, r5, r6, r7;
    const int buf = (t - 1) & 1;
    if (s == 0) {
      r0 = red[buf][0][o]; r1 = red[buf][1][o];
      r2 = red[buf][2][o]; r3 = red[buf][3][o];
      r4 = red[buf][4][o]; r5 = red[buf][5][o];
      r6 = red[buf][6][o]; r7 = red[buf][7][o];
    }
    LAYER1F();
    const int tn = (t + 1 < kT) ? (t + 1) : (kT - 1);
    LOADX(tn);
    if (s == 0) {
      float co = bout_o;
      co += r0; co += r1; co += r2; co += r3;
      co += r4; co += r5; co += r6; co += r7;
      memo = kBeta * memo + co - rsto;
      const float so = (memo > kThresh) ? 1.0f : 0.0f;
      rsto = so;
      out_mem[(t - 1) * kO] = memo;
      out_spk[(t - 1) * kO] = so;
    }
  }
  LAYER2F((kT - 1) & 1);
  BARRIER();
  if (s == 0) {
    const int buf = (kT - 1) & 1;
    float co = bout_o;
    co += red[buf][0][o]; co += red[buf][1][o];
    co += red[buf][2][o]; co += red[buf][3][o];
    co += red[buf][4][o]; co += red[buf][5][o];
    co += red[buf][6][o]; co += red[buf][7][o];
    memo = kBeta * memo + co - rsto;
    const float so = (memo > kThresh) ? 1.0f : 0.0f;
    out_mem[(kT - 1) * kO] = memo;
    out_spk[(kT - 1) * kO] = so;
  }
}

// ======================= host ==============================================
extern "C" void kernel_launch(void* const* d_in, const int* in_sizes, int n_in,
                              void* d_out, int out_size, void* d_ws,
                              size_t ws_size, hipStream_t stream) {
  const float* x = (const float*)d_in[0];
  const float* W_in = (const float*)d_in[1];
  const float* b_in = (const float*)d_in[2];
  const float* W_out = (const float*)d_in[3];
  const float* b_out = (const float*)d_in[4];
  float* out = (float*)d_out;

  const size_t state_bytes = ((size_t)2 * kB * kH + 2 * kB * kO) * 4;
  int nch = 0;
  for (int c : {4, 8, 16}) {   // nch=2 would spill cur1 past the 256MB L3
    const int ntc_c = kT / c;
    const size_t need = (size_t)kB * ntc_c * (kH + kO) * 4 + state_bytes;
    if (need <= ws_size) { nch = c; break; }
  }

  if (nch) {
    const int ntc = kT / nch;
    const int l2ntc = (ntc == 256) ? 8 : (ntc == 128) ? 7 : 6;
    float* cur1 = (float*)d_ws;                       // also spike buffer
    float* coutb = cur1 + (size_t)kB * ntc * kH;
    float* state = coutb + (size_t)kB * ntc * kO;

    const int rows = kB * ntc;
    const int rpbA = 64;
    const int gA = rows / rpbA;
    const int gC = rows / 64;

    for (int c = 0; c < nch; ++c) {
      const int t0 = c * ntc;
      hipLaunchKernelGGL(snn_curA, dim3(gA), dim3(256), 0, stream,
                         x, W_in, b_in, cur1, t0, ntc, l2ntc, rpbA);
      hipLaunchKernelGGL(snn_scanB, dim3(kB), dim3(512), 0, stream,
                         cur1, state, t0, ntc);
      hipLaunchKernelGGL(snn_coutC, dim3(gC), dim3(512), 0, stream,
                         cur1, W_out, b_out, coutb, ntc);
      hipLaunchKernelGGL(snn_memoD, dim3(kB), dim3(64), 0, stream,
                         coutb, out, state, t0, ntc);
    }
  } else {
    const int n4 = kB * kT * kF / 4;
    hipLaunchKernelGGL(warm_x_kernel, dim3(1024), dim3(256), 0, stream,
                       (const float4*)x, n4);
    hipLaunchKernelGGL(snn_fused5, dim3(kB), dim3(512), 0, stream,
                       x, W_in, b_in, W_out, b_out, out);
  }
}